// Round 4
// baseline (185.035 us; speedup 1.0000x reference)
//
#include <hip/hip_runtime.h>
#include <hip/hip_bf16.h>

// Problem constants
#define BB 16384
#define LL 9
#define DD 32
#define CR 128

typedef float v2 __attribute__((ext_vector_type(2)));

// ws layout (dwords):
//   [0 .. 8191]    AB interleaved: idx = d*256 + (c&63)*4 + {0:A1.lo, 1:A1.hi, 2:A2.lo, 3:A2.hi}
//                  where A1 = Wi@W1 (col c / c+64), A2 = Wj@W1
//   [8192 .. 10367] WK interleaved: idx = 8192 + k*128 + (c&63)*2 + (c>>6)
//                  WK[k] = (relpos_row_k@Wr + br + bi + bj)@W1 + b1, k = (i-j)+8 in 0..16

__global__ void precomp_kernel(const float* __restrict__ relpos,
                               const float* __restrict__ Wi, const float* __restrict__ bi,
                               const float* __restrict__ Wj, const float* __restrict__ bj,
                               const float* __restrict__ Wr, const float* __restrict__ br,
                               const float* __restrict__ W1, const float* __restrict__ b1,
                               float* __restrict__ ws)
{
    __shared__ float rv[DD];
    const int c = threadIdx.x;   // 0..127
    const int blk = blockIdx.x;  // 0..80
    const int cl = c & 63, ch = c >> 6;

    if (blk < 32) {
        const int d = blk;
        float s = 0.f;
        #pragma unroll
        for (int e = 0; e < DD; ++e) s = fmaf(Wi[d * DD + e], W1[e * CR + c], s);
        ws[d * 256 + cl * 4 + ch] = s;                 // A1 lanes
    } else if (blk < 64) {
        const int d = blk - 32;
        float s = 0.f;
        #pragma unroll
        for (int e = 0; e < DD; ++e) s = fmaf(Wj[d * DD + e], W1[e * CR + c], s);
        ws[d * 256 + cl * 4 + 2 + ch] = s;             // A2 lanes
    } else {
        const int k = blk - 64;       // 0..16, dk = k-8 = i-j
        const int dk = k - 8;
        const int i = dk > 0 ? dk : 0;
        const int j = i - dk;
        if (c < DD) {
            float s = bi[c] + bj[c] + br[c];
            #pragma unroll
            for (int d = 0; d < DD; ++d)
                s = fmaf(relpos[(i * LL + j) * DD + d], Wr[d * DD + c], s);
            rv[c] = s;
        }
        __syncthreads();
        float s = b1[c];
        #pragma unroll
        for (int e = 0; e < DD; ++e) s = fmaf(rv[e], W1[e * CR + c], s);
        ws[8192 + k * 128 + cl * 2 + ch] = s;
    }
}

// Main: 1 wave = 1 batch (grid-strided x4). Lane owns channel pair (c, c+64),
// packed v2 math throughout. AB tables live in LDS (one ds_read_b128 per d),
// wk/W2 in registers. No cross-wave reduction needed.
__global__ __launch_bounds__(256)
void outersum_main(const float* __restrict__ seq,
                   const float* __restrict__ ws,
                   const float* __restrict__ W2,
                   const float* __restrict__ b2,
                   float* __restrict__ out)
{
    __shared__ float lds_ab[8192];   // 32 KB

    const int tid = threadIdx.x;
    // Stage AB tables: straight 32 KB copy, coalesced float4.
    {
        const float4* src = (const float4*)ws;
        float4* dst = (float4*)lds_ab;
        #pragma unroll
        for (int t = 0; t < 8; ++t) dst[tid + t * 256] = src[tid + t * 256];
    }
    __syncthreads();

    const int lane = tid & 63;
    const int wave = __builtin_amdgcn_readfirstlane((blockIdx.x * 256 + tid) >> 6); // 0..4095

    // wk pairs: 17 x v2 from interleaved global (8B loads)
    v2 wk[17];
    const float* wkg = ws + 8192;
    #pragma unroll
    for (int k = 0; k < 17; ++k) wk[k] = *(const v2*)(wkg + k * 128 + lane * 2);

    // W2 rows for channels c and c+64
    const float2 w2a = ((const float2*)W2)[lane];
    const float2 w2b = ((const float2*)W2)[lane + 64];
    v2 w2o0; w2o0.x = w2a.x; w2o0.y = w2b.x;
    v2 w2o1; w2o1.x = w2a.y; w2o1.y = w2b.y;
    const float bias0 = 81.f * b2[0];
    const float bias1 = 81.f * b2[1];

    #pragma unroll 1
    for (int bi = 0; bi < 4; ++bi) {
        const int b = wave + bi * 4096;
        const float* __restrict__ sp = seq + (size_t)b * (LL * DD);

        // ---- U/V GEMV: d-outer (one ds_read_b128 each), i-inner ----
        v2 U[LL], V[LL];
        #pragma unroll
        for (int i = 0; i < LL; ++i) { U[i] = (v2)0.f; V[i] = (v2)0.f; }

        #pragma unroll
        for (int d = 0; d < DD; ++d) {
            const float4 ab = *(const float4*)&lds_ab[(d * 64 + lane) * 4];
            v2 a1p; a1p.x = ab.x; a1p.y = ab.y;
            v2 a2p; a2p.x = ab.z; a2p.y = ab.w;
            #pragma unroll
            for (int i = 0; i < LL; ++i) {
                const float s = sp[i * DD + d];   // wave-uniform -> s_load
                v2 s2; s2.x = s; s2.y = s;
                U[i] += s2 * a1p;
                V[i] += s2 * a2p;
            }
        }

        // ---- outer sum over diagonals k = i-j+8 (wk[k] hot per diagonal) ----
        v2 acc0 = (v2)0.f, acc1 = (v2)0.f;
        #pragma unroll
        for (int k = 0; k < 17; ++k) {
            const int dk = k - 8;
            const int i0 = dk > 0 ? dk : 0;
            const int cnt = LL - (dk > 0 ? dk : -dk);
            const v2 w = wk[k];
            #pragma unroll
            for (int t = 0; t < cnt; ++t) {
                const int i = i0 + t;
                const int j = i - dk;
                v2 tt = U[i] + V[j] + w;
                tt.x = fmaxf(tt.x, 0.f);
                tt.y = fmaxf(tt.y, 0.f);
                acc0 += tt * w2o0;
                acc1 += tt * w2o1;
            }
        }

        float r0 = acc0.x + acc0.y;
        float r1 = acc1.x + acc1.y;
        #pragma unroll
        for (int off = 32; off; off >>= 1) {
            r0 += __shfl_xor(r0, off, 64);
            r1 += __shfl_xor(r1, off, 64);
        }
        if (lane == 0) {
            float2 o; o.x = r0 + bias0; o.y = r1 + bias1;
            *(float2*)(out + (size_t)b * 2) = o;
        }
    }
}

extern "C" void kernel_launch(void* const* d_in, const int* in_sizes, int n_in,
                              void* d_out, int out_size, void* d_ws, size_t ws_size,
                              hipStream_t stream)
{
    const float* seq    = (const float*)d_in[0];
    const float* relpos = (const float*)d_in[1];
    const float* Wi     = (const float*)d_in[2];
    const float* bi     = (const float*)d_in[3];
    const float* Wj     = (const float*)d_in[4];
    const float* bj     = (const float*)d_in[5];
    const float* Wr     = (const float*)d_in[6];
    const float* br     = (const float*)d_in[7];
    const float* W1     = (const float*)d_in[8];
    const float* b1     = (const float*)d_in[9];
    const float* W2     = (const float*)d_in[10];
    const float* b2     = (const float*)d_in[11];
    float* out = (float*)d_out;
    float* ws  = (float*)d_ws;

    precomp_kernel<<<81, 128, 0, stream>>>(relpos, Wi, bi, Wj, bj, Wr, br, W1, b1, ws);

    // 1024 blocks x 4 waves = 4096 waves = 16 waves/CU resident; 4 batches/wave.
    outersum_main<<<1024, 256, 0, stream>>>(seq, ws, W2, b2, out);
}